// Round 3
// baseline (384.047 us; speedup 1.0000x reference)
//
#include <hip/hip_runtime.h>

// out[l, o*128+i, n, m] = sum_{j,kw} X(m+kw-1) * W[j,kw,i]
//   X(m') = 0 if m'<0 or m'>=28 else x[l, o*128+j, n1, (m'-1)%28],  n1=(n-1)%28
// LDS xsp[r][j] holds X(r-1): rows 0,29 zero; staging puts x[...,n1,m] at
// r = 1+(m+1)%28. Swizzle X(r)=(r>>1)&7 keeps ds_read_b128 uniform (8/bank)
// and makes staging writes ~2-way (free). 2-deep register pipeline with raw
// s_barrier so prefetch loads stay in flight across barriers.

typedef __bf16 bf16x8 __attribute__((ext_vector_type(8)));
typedef float  f32x4  __attribute__((ext_vector_type(4)));

__device__ __forceinline__ int swz(int r, int j) {
    return r * 128 + (j ^ (((r >> 1) & 7) << 3));
}

#define LOADROW(SET, T)                                                        \
    {                                                                          \
        SET[0] = *reinterpret_cast<const float4*>(cbase[0] + (T) * 28);        \
        SET[1] = *reinterpret_cast<const float4*>(cbase[1] + (T) * 28);        \
        SET[2] = *reinterpret_cast<const float4*>(cbase[2] + (T) * 28);        \
        if (v3) SET[3] = *reinterpret_cast<const float4*>(cbase[3] + (T) * 28);\
    }

#define STAGEROW(SET, BUF)                                                     \
    {                                                                          \
        _Pragma("unroll")                                                      \
        for (int c = 0; c < 4; ++c) {                                          \
            if (c < 3 || v3) {                                                 \
                _Pragma("unroll")                                              \
                for (int e = 0; e < 4; ++e) {                                  \
                    const int m = cm[c] * 4 + e;                               \
                    const int r = (m == 27) ? 1 : (m + 2);                     \
                    union { __bf16 h; unsigned short u; } cv;                  \
                    cv.h = (__bf16)((&SET[c].x)[e]);                           \
                    xsp[BUF][swz(r, cj[c])] = cv.u;                            \
                }                                                              \
            }                                                                  \
        }                                                                      \
    }

__global__ __launch_bounds__(256, 4)
void shiftconv_kernel(const float* __restrict__ x,
                      const float* __restrict__ Wm,
                      float* __restrict__ out)
{
    __shared__ unsigned short xsp[2][34 * 128];

    const int tid  = threadIdx.x;
    const int wave = tid >> 6;     // 0..3
    const int lane = tid & 63;
    const int l15  = lane & 15;
    const int hi2  = lane >> 4;    // 0..3

    const int b  = blockIdx.x;     // 2048 blocks
    const int l  = b >> 4;         // 0..127
    const int o  = (b >> 3) & 1;   // 0..1
    const int ih = (b >> 2) & 1;   // i-half
    const int nc = b & 3;          // 7 h-rows each

    const float* xbase = x   + (size_t)(l * 256 + o * 128) * 784 + nc * 7 * 28;
    float*       obase = out + (size_t)(l * 256 + o * 128) * 784;

    const int ig = ih * 64 + wave * 16 + l15;

    // ---- W fragments first (so in-loop vmcnt waits stay small/countable) ----
    bf16x8 bw[12];
#pragma unroll
    for (int s = 0; s < 12; ++s) {
        const int kw = s >> 2;
        const int jb = (s & 3) * 32 + hi2 * 8;
#pragma unroll
        for (int e = 0; e < 8; ++e)
            bw[s][e] = (__bf16)Wm[((jb + e) * 3 + kw) * 128 + ig];
    }

    // ---- staging chunk descriptors: 896 float4 = 128 j x 7 mq over 256 thr ----
    int cj[4], cm[4];
    const float* cbase[4];
#pragma unroll
    for (int c = 0; c < 4; ++c) {
        const int g = tid + 256 * c;
        const int j = g / 7;
        cj[c] = j;
        cm[c] = g - j * 7;
        cbase[c] = xbase + j * 784 + cm[c] * 4;
    }
    const bool v3 = (tid < 128);   // chunk 3 valid (waves 0,1) — wave-uniform

    // ---- zero pad rows 0 and 29 of both buffers ----
#pragma unroll
    for (int k = 0; k < 2; ++k) {
        const int idx = tid + 256 * k;          // 0..511
        const int bu  = idx >> 8;               // buffer
        const int r   = (idx & 128) ? 29 : 0;
        const int j   = idx & 127;
        xsp[bu][swz(r, j)] = 0;
    }

    float4 ra[4], rb[4];
    LOADROW(ra, 0);
    LOADROW(rb, 1);
    STAGEROW(ra, 0);                            // compiler: counted vmcnt (rb in flight)
    asm volatile("s_waitcnt lgkmcnt(0)" ::: "memory");
    __builtin_amdgcn_sched_barrier(0);
    __builtin_amdgcn_s_barrier();
    __builtin_amdgcn_sched_barrier(0);

#pragma unroll
    for (int t = 0; t < 7; ++t) {
        const int cur = t & 1;                  // buf holding row t

        // prefetch row t+2 into the just-freed register set (staged last iter)
        if (t + 2 < 7) {
            if (cur == 0) { LOADROW(ra, t + 2) } else { LOADROW(rb, t + 2) }
        }

        // ---- 24 MFMA from buf[cur] ----
        f32x4 acc0 = {0.f, 0.f, 0.f, 0.f};
        f32x4 acc1 = {0.f, 0.f, 0.f, 0.f};
        const unsigned short* xs = xsp[cur];
        __builtin_amdgcn_s_setprio(1);
#pragma unroll
        for (int s = 0; s < 12; ++s) {
            const int kw = s >> 2;
            const int jb = (s & 3) * 32 + hi2 * 8;
            const bf16x8 a0 = *reinterpret_cast<const bf16x8*>(&xs[swz(l15 + kw, jb)]);
            acc0 = __builtin_amdgcn_mfma_f32_16x16x32_bf16(a0, bw[s], acc0, 0, 0, 0);
            const bf16x8 a1 = *reinterpret_cast<const bf16x8*>(&xs[swz(16 + l15 + kw, jb)]);
            acc1 = __builtin_amdgcn_mfma_f32_16x16x32_bf16(a1, bw[s], acc1, 0, 0, 0);
        }
        __builtin_amdgcn_s_setprio(0);

        // ---- store: row m = mt*16 + hi2*4 + e, col i = ig ----
        const int n1 = nc * 7 + t;
        int n = n1 + 1; if (n == 28) n = 0;
        float* op = obase + (size_t)ig * 784 + n * 28;
        *reinterpret_cast<float4*>(op + hi2 * 4) =
            make_float4(acc0[0], acc0[1], acc0[2], acc0[3]);
        if (hi2 < 3)
            *reinterpret_cast<float4*>(op + 16 + hi2 * 4) =
                make_float4(acc1[0], acc1[1], acc1[2], acc1[3]);

        // ---- stage row t+1 into buf[cur^1] (loads issued one iter ago) ----
        if (t + 1 < 7) {
            if (cur == 0) { STAGEROW(rb, 1) } else { STAGEROW(ra, 0) }
            asm volatile("s_waitcnt lgkmcnt(0)" ::: "memory");
            __builtin_amdgcn_sched_barrier(0);
            __builtin_amdgcn_s_barrier();
            __builtin_amdgcn_sched_barrier(0);
        }
    }
}

extern "C" void kernel_launch(void* const* d_in, const int* in_sizes, int n_in,
                              void* d_out, int out_size, void* d_ws, size_t ws_size,
                              hipStream_t stream) {
    const float* x  = (const float*)d_in[0];   // (128, 256, 28, 28) fp32
    const float* Wm = (const float*)d_in[1];   // (128, 3, 128) fp32
    float* out = (float*)d_out;                // (128, 256, 28, 28) fp32
    hipLaunchKernelGGL(shiftconv_kernel, dim3(2048), dim3(256), 0, stream, x, Wm, out);
}

// Round 6
// 285.872 us; speedup vs baseline: 1.3434x; 1.3434x over previous
//
#include <hip/hip_runtime.h>

// out[l, o*128+i, n, m] = sum_{j,kw} X(m+kw-1) * W[j,kw,i]
//   X(m') = 0 if m'<0 or m'>=28 else x[l,o*128+j,n1,(m'-1)%28], n1=(n-1)%28
// Block = (l,o,nc): full i=128, 7 h-rows. Stage ALL 7 rows into LDS in one
// burst (one barrier), then 7 barrier-free MFMA+store iterations. Latency
// hiding via 2 resident blocks/CU overlapping (stream vs compute phases).
// LDS xs[t][r][j]: r=0,29 zero; x[...,m] at r=1+(m+1)%28; rows 30-33 garbage
// feed only discarded C cols m>=28. Swizzle (r>>1)&7 -> ~2-way on reads.
// MFMA operands swapped (A=W, B=x): C row=i, col=m -> stores are 64B runs.

typedef __bf16 bf16x8 __attribute__((ext_vector_type(8)));
typedef float  f32x4  __attribute__((ext_vector_type(4)));

__device__ __forceinline__ int swz(int t, int r, int j) {
    return (t * 34 + r) * 128 + (j ^ (((r >> 1) & 7) << 3));
}

__global__ __launch_bounds__(512, 4)
void shiftconv_kernel(const float* __restrict__ x,
                      const float* __restrict__ Wm,
                      float* __restrict__ out)
{
    __shared__ unsigned short xs[7 * 34 * 128];   // 59.5 KB

    const int tid  = threadIdx.x;
    const int wave = tid >> 6;      // 0..7
    const int lane = tid & 63;
    const int l15  = lane & 15;
    const int hi2  = lane >> 4;     // 0..3

    const int b  = blockIdx.x;      // 1024 blocks
    const int l  = b >> 3;
    const int o  = (b >> 2) & 1;
    const int nc = b & 3;           // 7 h-rows each

    const float* xbase = x   + (size_t)(l * 256 + o * 128) * 784 + nc * 7 * 28;
    float*       obase = out + (size_t)(l * 256 + o * 128) * 784;

    // ---- stage all 7 x-rows: 6272 float4 over 512 threads (13 chunks) ----
    float4 v[13];
    int toff[13], joff[13], moff[13];
#pragma unroll
    for (int c = 0; c < 13; ++c) {
        if (c < 12 || tid < 128) {                 // wave-uniform tail
            const int g   = tid + 512 * c;
            const int t   = g / 896;
            const int rem = g - t * 896;
            const int j   = rem / 7;
            const int mq  = rem - j * 7;
            toff[c] = t; joff[c] = j; moff[c] = mq;
            v[c] = *reinterpret_cast<const float4*>(xbase + j * 784 + t * 28 + mq * 4);
        }
    }

    // ---- W fragments (A-operand): bw[s][e] = W[(s&3)*32+hi2*8+e][s>>2][ig] ----
    const int ig = wave * 16 + l15;
    bf16x8 bw[12];
#pragma unroll
    for (int s = 0; s < 12; ++s) {
        const int kw = s >> 2;
        const int jb = (s & 3) * 32 + hi2 * 8;
#pragma unroll
        for (int e = 0; e < 8; ++e)
            bw[s][e] = (__bf16)Wm[((jb + e) * 3 + kw) * 128 + ig];
    }

    // ---- zero pad rows r=0,29 of each t (1792 entries) ----
#pragma unroll
    for (int k = 0; k < 4; ++k) {
        const int idx = tid + 512 * k;
        if (idx < 1792) {
            const int t = idx >> 8;
            const int r = (idx & 128) ? 29 : 0;
            const int j = idx & 127;
            xs[swz(t, r, j)] = 0;
        }
    }

    // ---- convert + LDS write (counted vmcnt waits; loads drain in order) ----
#pragma unroll
    for (int c = 0; c < 13; ++c) {
        if (c < 12 || tid < 128) {
#pragma unroll
            for (int e = 0; e < 4; ++e) {
                const int m = moff[c] * 4 + e;
                const int r = (m == 27) ? 1 : (m + 2);
                union { __bf16 h; unsigned short u; } cv;
                cv.h = (__bf16)((&v[c].x)[e]);
                xs[swz(toff[c], r, joff[c])] = cv.u;
            }
        }
    }

    __syncthreads();   // the only barrier

    // ---- 7 iterations: 24 MFMA + 8 coalesced store instrs, no barriers ----
#pragma unroll
    for (int t = 0; t < 7; ++t) {
        f32x4 acc0 = {0.f, 0.f, 0.f, 0.f};
        f32x4 acc1 = {0.f, 0.f, 0.f, 0.f};
#pragma unroll
        for (int s = 0; s < 12; ++s) {
            const int kw = s >> 2;
            const int jb = (s & 3) * 32 + hi2 * 8;
            const bf16x8 a0 = *reinterpret_cast<const bf16x8*>(&xs[swz(t, l15 + kw, jb)]);
            acc0 = __builtin_amdgcn_mfma_f32_16x16x32_bf16(bw[s], a0, acc0, 0, 0, 0);
            const bf16x8 a1 = *reinterpret_cast<const bf16x8*>(&xs[swz(t, 16 + l15 + kw, jb)]);
            acc1 = __builtin_amdgcn_mfma_f32_16x16x32_bf16(bw[s], a1, acc1, 0, 0, 0);
        }

        // C row = i-local = 4*hi2+e, col = m = l15 (+16). 64B runs per store.
        const int n = (nc * 7 + t + 1) % 28;
#pragma unroll
        for (int e = 0; e < 4; ++e) {
            float* op = obase + (size_t)(wave * 16 + 4 * hi2 + e) * 784 + n * 28;
            op[l15] = acc0[e];
            if (l15 < 12) op[16 + l15] = acc1[e];
        }
    }
}

extern "C" void kernel_launch(void* const* d_in, const int* in_sizes, int n_in,
                              void* d_out, int out_size, void* d_ws, size_t ws_size,
                              hipStream_t stream) {
    const float* x  = (const float*)d_in[0];   // (128, 256, 28, 28) fp32
    const float* Wm = (const float*)d_in[1];   // (128, 3, 128) fp32
    float* out = (float*)d_out;                // (128, 256, 28, 28) fp32
    hipLaunchKernelGGL(shiftconv_kernel, dim3(1024), dim3(512), 0, stream, x, Wm, out);
}

// Round 7
// 278.384 us; speedup vs baseline: 1.3796x; 1.0269x over previous
//
#include <hip/hip_runtime.h>

// out[l, o*128+i, n, m] = sum_{j,kw} X(m+kw-1) * W[j,kw,i]
//   X(m') = 0 if m'<0 or m'>=28 else x[l,o*128+j,n1,(m'-1)%28], n1=(n-1)%28
// Block = (l, o, nc): full i=128, ROWS=4 h-rows (nc in 0..6). Stage 4 rows
// into LDS (transposed items -> ds_write_b64), ONE barrier, then 4 barrier-
// free MFMA+store iterations. Swapped MFMA operands (A=W, B=x): C row=i,
// col=m -> stores are 64B runs. LDS xs[t][r][j]: r=0,29 zero; x[...,m] at
// r=1+(m+1)%28; rows 30-33 garbage feed only discarded C cols m>=28.
// Swizzle X=(r>>1)&7 on j bits 3..5: reads ~2-way (free), b64 writes ~2-way.

typedef __bf16 bf16x8 __attribute__((ext_vector_type(8)));
typedef float  f32x4  __attribute__((ext_vector_type(4)));
typedef unsigned short u16x4 __attribute__((ext_vector_type(4)));

__device__ __forceinline__ int swz(int t, int r, int j) {
    return (t * 34 + r) * 128 + (j ^ (((r >> 1) & 7) << 3));
}

__global__ __launch_bounds__(512, 6)
void shiftconv_kernel(const float* __restrict__ x,
                      const float* __restrict__ Wm,
                      float* __restrict__ out)
{
    __shared__ unsigned short xs[4 * 34 * 128];   // 34 KB

    const int tid  = threadIdx.x;
    const int wave = tid >> 6;      // 0..7
    const int lane = tid & 63;
    const int l15  = lane & 15;
    const int hi2  = lane >> 4;     // 0..3

    const int nc = blockIdx.x;      // 0..6  (4 h-rows each)
    const int o  = blockIdx.y;      // 0..1
    const int l  = blockIdx.z;      // 0..127

    const float* xbase = x   + (size_t)(l * 256 + o * 128) * 784 + nc * 4 * 28;
    float*       obase = out + (size_t)(l * 256 + o * 128) * 784;

    // ---- staging: 896 items = 4 t x 32 jg x 7 mq; item -> 4 float4 loads ----
    // item decode (compile-time divisors)
    const int itA = tid;
    const int itB = tid + 512;
    const bool vB = (tid < 384);            // wave-uniform (waves 6,7 skip)

    const int tA = itA / 224, remA = itA % 224;
    const int jgA = remA / 7,  mqA = remA % 7;
    const int tB = itB / 224, remB = itB % 224;
    const int jgB = remB / 7,  mqB = remB % 7;

    float4 va[4], vb[4];
#pragma unroll
    for (int jj = 0; jj < 4; ++jj)
        va[jj] = *reinterpret_cast<const float4*>(
            xbase + (4 * jgA + jj) * 784 + tA * 28 + mqA * 4);
#pragma unroll
    for (int jj = 0; jj < 4; ++jj)
        if (vB) vb[jj] = *reinterpret_cast<const float4*>(
            xbase + (4 * jgB + jj) * 784 + tB * 28 + mqB * 4);

    // ---- zero pad rows r=0,29 of each t (1024 entries / 512 thr) ----
#pragma unroll
    for (int k = 0; k < 2; ++k) {
        const int idx = tid + 512 * k;      // 0..1023
        const int t = idx >> 8;             // 0..3
        const int r = (idx & 128) ? 29 : 0;
        const int j = idx & 127;
        xs[swz(t, r, j)] = 0;
    }

    // ---- convert + ds_write_b64: one m-slice of 4 consecutive j per write ----
#pragma unroll
    for (int e = 0; e < 4; ++e) {
        const int m = mqA * 4 + e;
        const int r = (m == 27) ? 1 : (m + 2);
        union { __bf16 h; unsigned short u; } c0, c1, c2, c3;
        c0.h = (__bf16)((&va[0].x)[e]); c1.h = (__bf16)((&va[1].x)[e]);
        c2.h = (__bf16)((&va[2].x)[e]); c3.h = (__bf16)((&va[3].x)[e]);
        u16x4 p = {c0.u, c1.u, c2.u, c3.u};
        *reinterpret_cast<u16x4*>(&xs[swz(tA, r, 4 * jgA)]) = p;
    }
    if (vB) {
#pragma unroll
        for (int e = 0; e < 4; ++e) {
            const int m = mqB * 4 + e;
            const int r = (m == 27) ? 1 : (m + 2);
            union { __bf16 h; unsigned short u; } c0, c1, c2, c3;
            c0.h = (__bf16)((&vb[0].x)[e]); c1.h = (__bf16)((&vb[1].x)[e]);
            c2.h = (__bf16)((&vb[2].x)[e]); c3.h = (__bf16)((&vb[3].x)[e]);
            u16x4 p = {c0.u, c1.u, c2.u, c3.u};
            *reinterpret_cast<u16x4*>(&xs[swz(tB, r, 4 * jgB)]) = p;
        }
    }

    // ---- W fragments (A-operand), loaded after stage regs die ----
    const int ig = wave * 16 + l15;
    bf16x8 bw[12];
#pragma unroll
    for (int s = 0; s < 12; ++s) {
        const int kw = s >> 2;
        const int jb = (s & 3) * 32 + hi2 * 8;
#pragma unroll
        for (int e = 0; e < 8; ++e)
            bw[s][e] = (__bf16)Wm[((jb + e) * 3 + kw) * 128 + ig];
    }

    __syncthreads();   // the only barrier

    // ---- 4 iterations: 24 MFMA + stores, no barriers ----
#pragma unroll
    for (int t = 0; t < 4; ++t) {
        f32x4 acc0 = {0.f, 0.f, 0.f, 0.f};
        f32x4 acc1 = {0.f, 0.f, 0.f, 0.f};
#pragma unroll
        for (int s = 0; s < 12; ++s) {
            const int kw = s >> 2;
            const int jb = (s & 3) * 32 + hi2 * 8;
            const bf16x8 a0 = *reinterpret_cast<const bf16x8*>(&xs[swz(t, l15 + kw, jb)]);
            acc0 = __builtin_amdgcn_mfma_f32_16x16x32_bf16(bw[s], a0, acc0, 0, 0, 0);
            const bf16x8 a1 = *reinterpret_cast<const bf16x8*>(&xs[swz(t, 16 + l15 + kw, jb)]);
            acc1 = __builtin_amdgcn_mfma_f32_16x16x32_bf16(bw[s], a1, acc1, 0, 0, 0);
        }

        // C row = i-local = 4*hi2+e, col = m = l15 (+16). 64B runs per store.
        int n = nc * 4 + t + 1; if (n == 28) n = 0;
#pragma unroll
        for (int e = 0; e < 4; ++e) {
            float* op = obase + (size_t)(wave * 16 + 4 * hi2 + e) * 784 + n * 28;
            op[l15] = acc0[e];
            if (l15 < 12) op[16 + l15] = acc1[e];
        }
    }
}

extern "C" void kernel_launch(void* const* d_in, const int* in_sizes, int n_in,
                              void* d_out, int out_size, void* d_ws, size_t ws_size,
                              hipStream_t stream) {
    const float* x  = (const float*)d_in[0];   // (128, 256, 28, 28) fp32
    const float* Wm = (const float*)d_in[1];   // (128, 3, 128) fp32
    float* out = (float*)d_out;                // (128, 256, 28, 28) fp32
    hipLaunchKernelGGL(shiftconv_kernel, dim3(7, 2, 128), dim3(512), 0, stream, x, Wm, out);
}